// Round 5
// baseline (301.116 us; speedup 1.0000x reference)
//
#include <hip/hip_runtime.h>
#include <hip/hip_bf16.h>

#define CIN   512
#define COUT  512
#define LEN   8192
#define NB    16
#define KW    3
#define PROWS 8200          // padded l-rows per batch (p = l+1, l=-1..8193+slack)

#define WB_ELEMS (COUT * CIN * KW)
#define WB_BYTES ((size_t)WB_ELEMS * 2)
#define XS_BYTES ((size_t)NB * PROWS * CIN * 2)

// main kernel: 256x256 tile, BK=64, 8 waves (2Mx4N), 8-phase counted-vmcnt schedule
#define BM2 256
#define BN2 256
#define BK3 64
#define NT  ((CIN / BK3) * KW)        // 24 K-tiles, tap innermost
#define TILE3 (BM2 * BK3 * 2)         // 32 KB per operand tile

typedef __attribute__((ext_vector_type(4))) float f32x4;
typedef __attribute__((ext_vector_type(8))) short bf16x8;

static __device__ __forceinline__ unsigned short f2bf(float f) {
    union { float f; unsigned u; } cv; cv.f = f;
    return (unsigned short)((cv.u + 0x7fffu + ((cv.u >> 16) & 1u)) >> 16);
}

// ---- weight dequant-reorder: qweight[co][ci][t] (int32) -> wb[co][t*512+ci] (bf16) ----
__global__ __launch_bounds__(256) void wconv_kernel(const int* __restrict__ q,
                                                    unsigned short* __restrict__ wb) {
    int idx = blockIdx.x * 256 + threadIdx.x;
    if (idx >= WB_ELEMS) return;
    int co = idx / (KW * CIN);
    int r  = idx - co * (KW * CIN);
    int t  = r >> 9;
    int ci = r & 511;
    wb[idx] = f2bf((float)q[(co * CIN + ci) * KW + t]);
}

// ---- x prepass: fp32 [b][ci][l] -> bf16 [b][1+l][ci]; also zero halo rows ----
__global__ __launch_bounds__(256) void xprep_kernel(const float* __restrict__ x,
                                                    unsigned short* __restrict__ xs) {
    __shared__ char T[64 * 132];
    int blk = blockIdx.x;
    int b   = blk >> 10;
    int ci0 = ((blk >> 7) & 7) * 64;
    int l0  = (blk & 127) * 64;
    int tid = threadIdx.x;

    // fold zpad: first/last l-tile blocks zero the halo rows p=0 / p=8193 for their ci range
    if (l0 == 0 && tid < 64)
        xs[((size_t)b * PROWS + 0) * CIN + ci0 + tid] = 0;
    if (l0 == (LEN - 64) && tid < 64)
        xs[((size_t)b * PROWS + (LEN + 1)) * CIN + ci0 + tid] = 0;

    const float* src = x + ((size_t)b * CIN + ci0) * LEN + l0;
    for (int i = tid; i < 64 * 16; i += 256) {
        int r = i >> 4, c4 = i & 15;
        f32x4 v = *(const f32x4*)(src + (size_t)r * LEN + c4 * 4);
        unsigned lo = (unsigned)f2bf(v[0]) | ((unsigned)f2bf(v[1]) << 16);
        unsigned hi = (unsigned)f2bf(v[2]) | ((unsigned)f2bf(v[3]) << 16);
        char* p = T + r * 132 + c4 * 8;
        *(unsigned*)p       = lo;
        *(unsigned*)(p + 4) = hi;
    }
    __syncthreads();
    unsigned short* dst = xs + ((size_t)b * PROWS + 1 + l0) * CIN + ci0;
    for (int i = tid; i < 64 * 8; i += 256) {
        int l = i >> 3, c8 = i & 7;
        union { bf16x8 v; unsigned short s[8]; } pk;
        #pragma unroll
        for (int j = 0; j < 8; ++j)
            pk.s[j] = *(const unsigned short*)(T + (c8 * 8 + j) * 132 + l * 2);
        *(bf16x8*)(dst + (size_t)l * CIN + c8 * 8) = pk.v;
    }
}

// ---- main conv: 8-phase counted-vmcnt schedule, strength-reduced addressing ----
__global__ __launch_bounds__(512, 2) void conv_kernel(
    const unsigned short* __restrict__ xs,
    const unsigned short* __restrict__ wb,
    const float* __restrict__ scale_p,
    const float* __restrict__ bias,
    float* __restrict__ out)
{
    __shared__ char sA[2][TILE3];    // 2 x 32 KB
    __shared__ char sB[2][TILE3];    // 2 x 32 KB   (128 KiB total)

    const int bid = blockIdx.x;
    const int logical = (bid & 7) * 128 + (bid >> 3);   // XCD swizzle, 1024 = 8*128
    const int co_tile = logical & 1;
    const int l_tile  = logical >> 1;
    const int b   = l_tile >> 5;
    const int l0  = (l_tile & 31) * BN2;
    const int co0 = co_tile * BM2;

    const int tid  = threadIdx.x;
    const int lane = tid & 63;
    const int wid  = tid >> 6;
    const int wr   = wid >> 2;        // 0..1
    const int wc   = wid & 3;         // 0..3
    const int lhi  = lane >> 4;
    const int llo  = lane & 15;

    f32x4 acc[8][4] = {};             // row = m*32 + wr*16 (interleaved map)

    const char* xsB = (const char*)(xs + ((size_t)b * PROWS + l0) * CIN);
    const char* wbB = (const char*)wb + (size_t)co0 * (KW * CIN * 2);

    // ---- per-thread stage source pointers (incremental; delta per K-tile) ----
    const int it0 = tid, it1 = tid + 512;
    const int r0 = it0 >> 3, r1 = it1 >> 3;
    const int sw0 = ((it0 & 7) * 16) ^ ((r0 & 7) << 4);
    const int sw1 = ((it1 & 7) * 16) ^ ((r1 & 7) << 4);
    const char* pBs[4] = { xsB + r0 * 1024 + sw0,          xsB + r1 * 1024 + sw1,
                           xsB + (128 + r0) * 1024 + sw0,  xsB + (128 + r1) * 1024 + sw1 };
    const char* pAs[4] = { wbB + (size_t)r0 * 3072 + sw0,         wbB + (size_t)r1 * 3072 + sw1,
                           wbB + (size_t)(128 + r0) * 3072 + sw0, wbB + (size_t)(128 + r1) * 3072 + sw1 };
    const int d0 = tid * 16, d1 = d0 + 8192;

    // ---- per-thread LDS read bases: off(mq,k) = base_k + mq*4096 ; off(n,k) = base_k + n*2048 ----
    const int s10 = llo & 3, s2 = (llo >> 2) & 1;
    const int constA = (wr * 16 + llo) * 128 + ((lhi ^ s10) << 4);
    const int constB = (wc * 64 + llo) * 128 + ((lhi ^ s10) << 4);
    const char* pA0b = &sA[0][0] + constA + (s2 ? 64 : 0);   // k=0
    const char* pA1b = &sA[0][0] + constA + (s2 ? 0 : 64);   // k=1
    const char* pB0b = &sB[0][0] + constB + (s2 ? 64 : 0);
    const char* pB1b = &sB[0][0] + constB + (s2 ? 0 : 64);

#define STAGEU(buf_, u_) do {                                                                \
    const char* s0_; const char* s1_; char* dd_;                                             \
    if ((u_) == 0)      { s0_ = pBs[0]; s1_ = pBs[1]; dd_ = &sB[buf_][0];     }              \
    else if ((u_) == 1) { s0_ = pBs[2]; s1_ = pBs[3]; dd_ = &sB[buf_][16384]; }              \
    else if ((u_) == 2) { s0_ = pAs[0]; s1_ = pAs[1]; dd_ = &sA[buf_][0];     }              \
    else                { s0_ = pAs[2]; s1_ = pAs[3]; dd_ = &sA[buf_][16384]; }              \
    __builtin_amdgcn_global_load_lds(                                                        \
        (const __attribute__((address_space(1))) unsigned int*)s0_,                          \
        (__attribute__((address_space(3))) unsigned int*)(dd_ + d0), 16, 0, 0);              \
    __builtin_amdgcn_global_load_lds(                                                        \
        (const __attribute__((address_space(1))) unsigned int*)s1_,                          \
        (__attribute__((address_space(3))) unsigned int*)(dd_ + d1), 16, 0, 0);              \
    } while (0)

#define RDA(p_, mq_) (*(const bf16x8*)((p_) + (mq_) * 4096))
#define RDB(p_, n_)  (*(const bf16x8*)((p_) + (n_) * 2048))

#define MFMA16(mb_, B0_, B1_, B2_, B3_) do {                                                 \
    __builtin_amdgcn_s_setprio(1);                                                           \
    acc[(mb_)+0][0] = __builtin_amdgcn_mfma_f32_16x16x32_bf16(a0_, B0_, acc[(mb_)+0][0],0,0,0); \
    acc[(mb_)+0][1] = __builtin_amdgcn_mfma_f32_16x16x32_bf16(a0_, B1_, acc[(mb_)+0][1],0,0,0); \
    acc[(mb_)+0][2] = __builtin_amdgcn_mfma_f32_16x16x32_bf16(a0_, B2_, acc[(mb_)+0][2],0,0,0); \
    acc[(mb_)+0][3] = __builtin_amdgcn_mfma_f32_16x16x32_bf16(a0_, B3_, acc[(mb_)+0][3],0,0,0); \
    acc[(mb_)+1][0] = __builtin_amdgcn_mfma_f32_16x16x32_bf16(a1_, B0_, acc[(mb_)+1][0],0,0,0); \
    acc[(mb_)+1][1] = __builtin_amdgcn_mfma_f32_16x16x32_bf16(a1_, B1_, acc[(mb_)+1][1],0,0,0); \
    acc[(mb_)+1][2] = __builtin_amdgcn_mfma_f32_16x16x32_bf16(a1_, B2_, acc[(mb_)+1][2],0,0,0); \
    acc[(mb_)+1][3] = __builtin_amdgcn_mfma_f32_16x16x32_bf16(a1_, B3_, acc[(mb_)+1][3],0,0,0); \
    acc[(mb_)+2][0] = __builtin_amdgcn_mfma_f32_16x16x32_bf16(a2_, B0_, acc[(mb_)+2][0],0,0,0); \
    acc[(mb_)+2][1] = __builtin_amdgcn_mfma_f32_16x16x32_bf16(a2_, B1_, acc[(mb_)+2][1],0,0,0); \
    acc[(mb_)+2][2] = __builtin_amdgcn_mfma_f32_16x16x32_bf16(a2_, B2_, acc[(mb_)+2][2],0,0,0); \
    acc[(mb_)+2][3] = __builtin_amdgcn_mfma_f32_16x16x32_bf16(a2_, B3_, acc[(mb_)+2][3],0,0,0); \
    acc[(mb_)+3][0] = __builtin_amdgcn_mfma_f32_16x16x32_bf16(a3_, B0_, acc[(mb_)+3][0],0,0,0); \
    acc[(mb_)+3][1] = __builtin_amdgcn_mfma_f32_16x16x32_bf16(a3_, B1_, acc[(mb_)+3][1],0,0,0); \
    acc[(mb_)+3][2] = __builtin_amdgcn_mfma_f32_16x16x32_bf16(a3_, B2_, acc[(mb_)+3][2],0,0,0); \
    acc[(mb_)+3][3] = __builtin_amdgcn_mfma_f32_16x16x32_bf16(a3_, B3_, acc[(mb_)+3][3],0,0,0); \
    __builtin_amdgcn_s_setprio(0);                                                           \
    } while (0)

#define BAR()    __builtin_amdgcn_s_barrier()
#define SCHED0() __builtin_amdgcn_sched_barrier(0)
#define LGKM0()  asm volatile("s_waitcnt lgkmcnt(0)" ::: "memory")

    // prologue: stage all 4 units of tile 0; u0,u1,u2 must land before p0 reads
    STAGEU(0, 0); STAGEU(0, 1); STAGEU(0, 2); STAGEU(0, 3);
    {   // advance stage pointers tile0 -> tile1 (tap 0->1: +1024B)
        #pragma unroll
        for (int i = 0; i < 4; ++i) { pBs[i] += 1024; pAs[i] += 1024; }
    }
    int tapn = 1;                     // tap of next-staged tile (tile 1)
    asm volatile("s_waitcnt vmcnt(2)" ::: "memory");
    BAR();

    bf16x8 a0_, a1_, a2_, a3_;
    bf16x8 bk00, bk01, bk02, bk03;    // B k=0, n=0..3
    bf16x8 bk10, bk11, bk12, bk13;    // B k=1, n=0..3

    #pragma unroll 1
    for (int c = 0; c < NT - 1; ++c) {
        const int buf = c & 1, nb = buf ^ 1;
        const int bufo = buf << 15;
        const char* cpA0 = pA0b + bufo;
        const char* cpA1 = pA1b + bufo;
        const char* cpB0 = pB0b + bufo;
        const char* cpB1 = pB1b + bufo;

        // ---- p0: B k=0 (4) + A mq0-3 k=0 (4); stage u0(next) ----
        SCHED0();
        bk00 = RDB(cpB0, 0); bk01 = RDB(cpB0, 1); bk02 = RDB(cpB0, 2); bk03 = RDB(cpB0, 3);
        a0_ = RDA(cpA0, 0); a1_ = RDA(cpA0, 1); a2_ = RDA(cpA0, 2); a3_ = RDA(cpA0, 3);
        STAGEU(nb, 0);
        BAR(); LGKM0(); SCHED0();
        MFMA16(0, bk00, bk01, bk02, bk03);
        BAR();
        // ---- p1: B k=1 (4) + A mq0-3 k=1 (4); stage u1(next); ensure Ah1(cur) landed ----
        SCHED0();
        bk10 = RDB(cpB1, 0); bk11 = RDB(cpB1, 1); bk12 = RDB(cpB1, 2); bk13 = RDB(cpB1, 3);
        a0_ = RDA(cpA1, 0); a1_ = RDA(cpA1, 1); a2_ = RDA(cpA1, 2); a3_ = RDA(cpA1, 3);
        STAGEU(nb, 1);
        asm volatile("s_waitcnt vmcnt(4)" ::: "memory");
        BAR(); LGKM0(); SCHED0();
        MFMA16(0, bk10, bk11, bk12, bk13);
        BAR();
        // ---- p2: A mq4-7 k=0 (4); stage u2(next); B k=0 regs still live ----
        SCHED0();
        a0_ = RDA(cpA0, 4); a1_ = RDA(cpA0, 5); a2_ = RDA(cpA0, 6); a3_ = RDA(cpA0, 7);
        STAGEU(nb, 2);
        BAR(); LGKM0(); SCHED0();
        MFMA16(4, bk00, bk01, bk02, bk03);
        BAR();
        // ---- p3: A mq4-7 k=1 (4); stage u3(next); ensure u0,u1,u2(next) landed ----
        SCHED0();
        a0_ = RDA(cpA1, 4); a1_ = RDA(cpA1, 5); a2_ = RDA(cpA1, 6); a3_ = RDA(cpA1, 7);
        STAGEU(nb, 3);
        asm volatile("s_waitcnt vmcnt(2)" ::: "memory");
        BAR(); LGKM0(); SCHED0();
        MFMA16(4, bk10, bk11, bk12, bk13);
        BAR();

        // advance stage pointers to tile c+2
        const int kd = (tapn == 2) ? -1920 : 1024;
        tapn = (tapn == 2) ? 0 : tapn + 1;
        #pragma unroll
        for (int i = 0; i < 4; ++i) { pBs[i] += kd; pAs[i] += kd; }
    }
    // ---- peeled tail tile (no stages); drain with vmcnt(0) before Ah1 reads ----
    {
        const int bufo = ((NT - 1) & 1) << 15;
        const char* cpA0 = pA0b + bufo;
        const char* cpA1 = pA1b + bufo;
        const char* cpB0 = pB0b + bufo;
        const char* cpB1 = pB1b + bufo;
        SCHED0();
        bk00 = RDB(cpB0, 0); bk01 = RDB(cpB0, 1); bk02 = RDB(cpB0, 2); bk03 = RDB(cpB0, 3);
        a0_ = RDA(cpA0, 0); a1_ = RDA(cpA0, 1); a2_ = RDA(cpA0, 2); a3_ = RDA(cpA0, 3);
        BAR(); LGKM0(); SCHED0();
        MFMA16(0, bk00, bk01, bk02, bk03);
        BAR();
        SCHED0();
        bk10 = RDB(cpB1, 0); bk11 = RDB(cpB1, 1); bk12 = RDB(cpB1, 2); bk13 = RDB(cpB1, 3);
        a0_ = RDA(cpA1, 0); a1_ = RDA(cpA1, 1); a2_ = RDA(cpA1, 2); a3_ = RDA(cpA1, 3);
        asm volatile("s_waitcnt vmcnt(0)" ::: "memory");
        BAR(); LGKM0(); SCHED0();
        MFMA16(0, bk10, bk11, bk12, bk13);
        BAR();
        SCHED0();
        a0_ = RDA(cpA0, 4); a1_ = RDA(cpA0, 5); a2_ = RDA(cpA0, 6); a3_ = RDA(cpA0, 7);
        BAR(); LGKM0(); SCHED0();
        MFMA16(4, bk00, bk01, bk02, bk03);
        BAR();
        SCHED0();
        a0_ = RDA(cpA1, 4); a1_ = RDA(cpA1, 5); a2_ = RDA(cpA1, 6); a3_ = RDA(cpA1, 7);
        LGKM0(); SCHED0();
        MFMA16(4, bk10, bk11, bk12, bk13);
    }
#undef STAGEU
#undef RDA
#undef RDB
#undef MFMA16

    const float sc = scale_p[0];
    #pragma unroll
    for (int m = 0; m < 8; ++m) {
        #pragma unroll
        for (int j = 0; j < 4; ++j) {
            int co = co0 + m * 32 + wr * 16 + lhi * 4 + j;
            float bv = bias[co];
            size_t orow = ((size_t)b * COUT + co) * LEN + l0 + wc * 64;
            #pragma unroll
            for (int n = 0; n < 4; ++n)
                out[orow + n * 16 + llo] = sc * acc[m][n][j] + bv;
        }
    }
}

// ---- fallback (no x prepass) — only if ws too small ----
__global__ __launch_bounds__(256, 2) void conv_fb_kernel(
    const float* __restrict__ x,
    const unsigned short* __restrict__ wb,
    const float* __restrict__ scale_p,
    const float* __restrict__ bias,
    float* __restrict__ out)
{
    __shared__ char xT[132 * 128];
    const int bid = blockIdx.x;
    const int logical = (bid & 7) * 512 + (bid >> 3);
    const int co_tile = logical & 3;
    const int n_tile  = logical >> 2;
    const int b   = n_tile >> 6;
    const int l0  = (n_tile & 63) * 128;
    const int co0 = co_tile * 128;
    const int tid  = threadIdx.x;
    const int lane = tid & 63;
    const int wid  = tid >> 6;
    const int wr = wid >> 1, wc = wid & 1;
    const int lhi = lane >> 4;
    const int llo = lane & 15;
    f32x4 acc[4][4] = {};
    const float* xb = x + (size_t)b * CIN * LEN;

    for (int ci0 = 0; ci0 < CIN; ci0 += 64) {
        __syncthreads();
        for (int it = tid; it < 132 * 8; it += 256) {
            int c = it % 132;
            int o = it / 132;
            int l = l0 - 1 + c;
            float v[8];
            if (l >= 0 && l < LEN) {
                const float* src = xb + (size_t)(ci0 + o * 8) * LEN + l;
                #pragma unroll
                for (int j = 0; j < 8; ++j) v[j] = src[(size_t)j * LEN];
            } else {
                #pragma unroll
                for (int j = 0; j < 8; ++j) v[j] = 0.f;
            }
            union { bf16x8 v8; unsigned short s[8]; } pk;
            #pragma unroll
            for (int j = 0; j < 8; ++j) pk.s[j] = f2bf(v[j]);
            int byte = c * 128 + ((o * 16) ^ ((c & 7) << 4));
            *reinterpret_cast<bf16x8*>(xT + byte) = pk.v8;
        }
        __syncthreads();
        #pragma unroll
        for (int t = 0; t < KW; ++t) {
            #pragma unroll
            for (int s = 0; s < 2; ++s) {
                bf16x8 af[4];
                #pragma unroll
                for (int m = 0; m < 4; ++m)
                    af[m] = *reinterpret_cast<const bf16x8*>(
                        wb + (size_t)(co0 + wr * 64 + m * 16 + llo) * (KW * CIN)
                           + t * CIN + ci0 + s * 32 + 8 * lhi);
                bf16x8 bfr[4];
                #pragma unroll
                for (int n = 0; n < 4; ++n) {
                    int col = wc * 64 + n * 16 + llo + t;
                    int byte = col * 128 + (((s * 32 + 8 * lhi) * 2) ^ ((col & 7) << 4));
                    bfr[n] = *reinterpret_cast<const bf16x8*>(xT + byte);
                }
                #pragma unroll
                for (int m = 0; m < 4; ++m)
                    #pragma unroll
                    for (int n = 0; n < 4; ++n)
                        acc[m][n] = __builtin_amdgcn_mfma_f32_16x16x32_bf16(af[m], bfr[n], acc[m][n], 0, 0, 0);
            }
        }
    }
    const float sc = scale_p[0];
    #pragma unroll
    for (int m = 0; m < 4; ++m) {
        #pragma unroll
        for (int j = 0; j < 4; ++j) {
            int co = co0 + wr * 64 + m * 16 + lhi * 4 + j;
            float bv = bias[co];
            size_t orow = ((size_t)b * COUT + co) * LEN + l0 + wc * 64;
            #pragma unroll
            for (int n = 0; n < 4; ++n)
                out[orow + n * 16 + llo] = sc * acc[m][n][j] + bv;
        }
    }
}

extern "C" void kernel_launch(void* const* d_in, const int* in_sizes, int n_in,
                              void* d_out, int out_size, void* d_ws, size_t ws_size,
                              hipStream_t stream) {
    const float* x    = (const float*)d_in[0];
    const int*   qw   = (const int*)d_in[1];
    const float* sc   = (const float*)d_in[2];
    const float* bias = (const float*)d_in[3];
    float* out = (float*)d_out;
    unsigned short* wb = (unsigned short*)d_ws;

    wconv_kernel<<<(WB_ELEMS + 255) / 256, 256, 0, stream>>>(qw, wb);

    if (ws_size >= WB_BYTES + XS_BYTES) {
        unsigned short* xsw = (unsigned short*)((char*)d_ws + WB_BYTES);
        xprep_kernel<<<NB * 8 * (LEN / 64), 256, 0, stream>>>(x, xsw);
        conv_kernel<<<(COUT / BM2) * (NB * LEN / BN2), 512, 0, stream>>>(xsw, wb, sc, bias, out);
    } else {
        conv_fb_kernel<<<4096, 256, 0, stream>>>(x, wb, sc, bias, out);
    }
}